// Round 2
// baseline (2480.376 us; speedup 1.0000x reference)
//
#include <hip/hip_runtime.h>

#define E 64
#define D 50
#define SS 384
#define G4 256   // 4*E

__device__ __forceinline__ float fast_rcp(float x){ return __builtin_amdgcn_rcpf(x); }
__device__ __forceinline__ float tanh_fast(float x){
  // tanh(x) = 1 - 2/(exp(2x)+1); exp overflow->inf->+1, underflow->0->-1 (both correct)
  float e = __expf(2.0f*x);
  return 1.0f - 2.0f*fast_rcp(e + 1.0f);
}
__device__ __forceinline__ float sigmoid_fast(float x){
  return fast_rcp(1.0f + __expf(-x));
}
__device__ __forceinline__ float bcast_lane(float v, int lane){
  return __int_as_float(__builtin_amdgcn_readlane(__float_as_int(v), lane));
}

// ---------------------------------------------------------------------------
// K0: gx[b,s,j] = bias[j] + sum_k emb[sent[b,s],k] * Wih[j,k]   (both LSTMs)
// ---------------------------------------------------------------------------
__global__ __launch_bounds__(256) void gx_kernel(
  const int* __restrict__ sent1, const int* __restrict__ sent2,
  const float* __restrict__ emb,
  const float* __restrict__ Wih1, const float* __restrict__ bih1, const float* __restrict__ bhh1,
  const float* __restrict__ Wih2, const float* __restrict__ bih2, const float* __restrict__ bhh2,
  float* __restrict__ gx1, float* __restrict__ gx2)
{
  const int bb    = blockIdx.x;     // 0..511
  const int which = bb >> 8;
  const int chunk = bb & 255;
  const int j     = threadIdx.x;
  const int*   sent = which ? sent2 : sent1;
  const float* Wih  = which ? Wih2  : Wih1;
  const float* bA   = which ? bih2  : bih1;
  const float* bB   = which ? bhh2  : bhh1;
  float*       gx   = which ? gx2   : gx1;

  float wih[D];
  #pragma unroll
  for (int k=0;k<D;k+=2){
    float2 v = *(const float2*)&Wih[j*D+k];
    wih[k]=v.x; wih[k+1]=v.y;
  }
  const float bias = bA[j] + bB[j];

  __shared__ __align__(16) float xb[8][52];
  const int row0 = chunk*96;
  for (int c=0;c<12;++c){
    const int r0 = row0 + c*8;
    #pragma unroll
    for (int q=0;q<2;++q){
      int tt = j + q*256;
      if (tt < 400){
        int r = tt/50;
        int k = tt - r*50;
        int idx = sent[r0 + r];
        xb[r][k] = emb[(size_t)idx*D + k];
      }
    }
    __syncthreads();
    for (int r=0;r<8;++r){
      float a0=bias, a1=0.f;
      #pragma unroll
      for (int k=0;k<48;k+=4){
        float4 xv = *(const float4*)&xb[r][k];
        a0 += xv.x*wih[k]   + xv.y*wih[k+1];
        a1 += xv.z*wih[k+2] + xv.w*wih[k+3];
      }
      a0 += xb[r][48]*wih[48];
      a1 += xb[r][49]*wih[49];
      gx[(size_t)(r0+r)*G4 + j] = a0+a1;
    }
    __syncthreads();
  }
}

// ---------------------------------------------------------------------------
// K1: both LSTM recurrences. 64 blocks (one per batch) x 256 threads.
// ---------------------------------------------------------------------------
__global__ __launch_bounds__(256) void lstm_kernel(
  const float* __restrict__ gx1, const float* __restrict__ gx2,
  const float* __restrict__ Whh1, const float* __restrict__ Whh2,
  const int* __restrict__ s1_len, const int* __restrict__ s2_len,
  float* __restrict__ h1_all, float* __restrict__ out_all,
  float* __restrict__ hn_cap)
{
  const int b = blockIdx.x;
  const int j = threadIdx.x;
  __shared__ __align__(16) float h_lds[E];
  __shared__ float gates[G4];
  float whh[E];
  #pragma unroll
  for (int k=0;k<E;k+=4){
    float4 v = *(const float4*)&Whh1[j*E+k];
    whh[k]=v.x; whh[k+1]=v.y; whh[k+2]=v.z; whh[k+3]=v.w;
  }
  const int is_g_gate = (j>=128 && j<192);
  float c_reg=0.f, gh=0.f, gc=0.f, hn=0.f;
  int idx1 = 0, idx2 = 0;
  if (j<E){ idx1 = s1_len[b*E+j]; idx2 = s2_len[b*E+j]; h_lds[j]=0.f; }
  __syncthreads();

  // ---- LSTM1 ----
  {
    const float* gx = gx1 + (size_t)b*SS*G4;
    float* hout = h1_all + (size_t)b*SS*E;
    float gx_cur = gx[j];
    float gx_n1  = gx[G4 + j];
    for (int s=0;s<SS;++s){
      int sn2 = (s+2<SS)? s+2 : SS-1;
      float gx_n2 = gx[(size_t)sn2*G4 + j];
      float a0=0,a1=0,a2=0,a3=0;
      #pragma unroll
      for (int k=0;k<E;k+=4){
        float4 hv = *(const float4*)&h_lds[k];
        a0 += hv.x*whh[k];   a1 += hv.y*whh[k+1];
        a2 += hv.z*whh[k+2]; a3 += hv.w*whh[k+3];
      }
      float g = ((a0+a1)+(a2+a3)) + gx_cur;
      gates[j] = is_g_gate ? tanh_fast(g) : sigmoid_fast(g);
      __syncthreads();
      if (j<E){
        float gi=gates[j], gf=gates[E+j], gg=gates[2*E+j], go=gates[3*E+j];
        c_reg = gf*c_reg + gi*gg;
        float h = go * tanh_fast(c_reg);
        h_lds[j] = h;
        hout[(size_t)s*E + j] = h;
        if (s==idx1){ gh=h; gc=c_reg; }
      }
      gx_cur = gx_n1; gx_n1 = gx_n2;
      __syncthreads();
    }
  }
  // ---- LSTM2 ----
  #pragma unroll
  for (int k=0;k<E;k+=4){
    float4 v = *(const float4*)&Whh2[j*E+k];
    whh[k]=v.x; whh[k+1]=v.y; whh[k+2]=v.z; whh[k+3]=v.w;
  }
  if (j<E){ h_lds[j]=gh; c_reg=gc; }
  __syncthreads();
  {
    const float* gx = gx2 + (size_t)b*SS*G4;
    float* hout = out_all + (size_t)b*SS*E;
    float gx_cur = gx[j];
    float gx_n1  = gx[G4 + j];
    for (int s=0;s<SS;++s){
      int sn2 = (s+2<SS)? s+2 : SS-1;
      float gx_n2 = gx[(size_t)sn2*G4 + j];
      float a0=0,a1=0,a2=0,a3=0;
      #pragma unroll
      for (int k=0;k<E;k+=4){
        float4 hv = *(const float4*)&h_lds[k];
        a0 += hv.x*whh[k];   a1 += hv.y*whh[k+1];
        a2 += hv.z*whh[k+2]; a3 += hv.w*whh[k+3];
      }
      float g = ((a0+a1)+(a2+a3)) + gx_cur;
      gates[j] = is_g_gate ? tanh_fast(g) : sigmoid_fast(g);
      __syncthreads();
      if (j<E){
        float gi=gates[j], gf=gates[E+j], gg=gates[2*E+j], go=gates[3*E+j];
        c_reg = gf*c_reg + gi*gg;
        float h = go * tanh_fast(c_reg);
        h_lds[j] = h;
        hout[(size_t)s*E + j] = h;
        if (s==idx2) hn = h;
      }
      gx_cur = gx_n1; gx_n1 = gx_n2;
      __syncthreads();
    }
  }
  if (j<E) hn_cap[b*E+j] = hn;
}

// ---------------------------------------------------------------------------
// K2: T[row,f] = tanh( sum_e h1[row,e]*wy[e,f] + out[row,e]*wh[e,f] )
// (tanh folded here so attn's hot loop can use the tanh addition formula)
// ---------------------------------------------------------------------------
__global__ __launch_bounds__(256) void base_kernel(
  const float* __restrict__ h1_all, const float* __restrict__ out_all,
  const float* __restrict__ wy, const float* __restrict__ wh,
  float* __restrict__ T_g)
{
  const int t = threadIdx.x;
  const int wave = t>>6, lane = t&63;
  float wyc[E], whc[E];
  #pragma unroll
  for (int e=0;e<E;++e){ wyc[e]=wy[e*E+lane]; whc[e]=wh[e*E+lane]; }
  const int row0 = blockIdx.x*16 + wave*4;
  for (int r=0;r<4;++r){
    int row = row0 + r;
    float hv = h1_all[(size_t)row*E + lane];
    float ov = out_all[(size_t)row*E + lane];
    float a0=0,a1=0;
    #pragma unroll
    for (int e=0;e<E;++e){
      a0 += bcast_lane(hv,e)*wyc[e];
      a1 += bcast_lane(ov,e)*whc[e];
    }
    T_g[(size_t)row*E + lane] = tanh_fast(a0+a1);
  }
}

// ---------------------------------------------------------------------------
// K3: attention scan. 64 blocks x 1024 threads, 384 sequential steps.
// T/h/s1_s live in REGISTERS across all steps (no global traffic in loop).
// tanh(base+rw) = (T+tb)*rcp(1+T*tb): 1 trans/element instead of 2.
// Cross-wave reduce via LDS atomics; GEMVs (rnew@wr, rnew@wt) split over
// all 16 waves. Triple-buffered accumulators -> 2 barriers/step.
// ---------------------------------------------------------------------------
__global__ __launch_bounds__(1024) void attn_kernel(
  const float* __restrict__ h1_all, const float* __restrict__ T_all,
  const float* __restrict__ w, const float* __restrict__ wr, const float* __restrict__ wt,
  const float* __restrict__ s1_s, const int* __restrict__ s2_len,
  float* __restrict__ rn_cap)
{
  const int b = blockIdx.x;
  const int t = threadIdx.x;
  const int wave = t>>6, lane = t&63;
  const int sub = t&15, e4 = sub*4;
  const int srow0 = t>>4;      // 0..63

  __shared__ float attn_acc[3][66];   // [][64] = total exp sum
  __shared__ float rw_buf[3][64];
  __shared__ float rt_buf[3][64];

  const float* h1b = h1_all + (size_t)b*SS*E;
  const float* Tb  = T_all  + (size_t)b*SS*E;

  // ---- preload everything into registers ----
  float4 Tq[6], hq[6]; float s1v[6];
  #pragma unroll
  for (int p=0;p<6;++p){
    int srow = srow0 + p*64;
    Tq[p]  = *(const float4*)&Tb[(size_t)srow*E + e4];
    hq[p]  = *(const float4*)&h1b[(size_t)srow*E + e4];
    s1v[p] = s1_s[b*SS + srow];
  }
  const float4 wv4 = *(const float4*)&w[e4];
  float wch[8];
  {
    const float* Wsel = (wave<8) ? wr : wt;
    int k0 = (wave&7)*8;
    #pragma unroll
    for (int j=0;j<8;++j) wch[j] = Wsel[(k0+j)*E + lane];
  }
  const int idx2 = s2_len[b*E + lane];
  float rn_keep = 0.f;

  // zero all buffers
  if (t < 3*66) (&attn_acc[0][0])[t] = 0.f;
  else if (t < 3*66 + 3*64) (&rw_buf[0][0])[t - 3*66] = 0.f;
  else if (t < 3*66 + 6*64) (&rt_buf[0][0])[t - 3*66 - 3*64] = 0.f;
  __syncthreads();

  for (int s=0;s<SS;++s){
    const int cur = s%3, nxt = (s+1)%3, z = (s+2)%3;

    // zero-duty for step s+2's accumulators (buffers nobody touches this step)
    if (t < 66) attn_acc[z][t] = 0.f;
    else if (t < 130) rw_buf[z][t-66] = 0.f;
    else if (t < 194) rt_buf[z][t-130] = 0.f;

    // tb = tanh(rw[e]) : one tanh per lane (e=lane), bpermute the 4 we need
    float tbl = tanh_fast(rw_buf[cur][lane]);
    float tb0 = __shfl(tbl, e4+0);
    float tb1 = __shfl(tbl, e4+1);
    float tb2 = __shfl(tbl, e4+2);
    float tb3 = __shfl(tbl, e4+3);

    float ax=0.f, ay=0.f, az=0.f, aw=0.f, sum_acc=0.f;
    #pragma unroll
    for (int p=0;p<6;++p){
      float n0 = Tq[p].x + tb0, d0 = __builtin_fmaf(Tq[p].x, tb0, 1.0f);
      float n1 = Tq[p].y + tb1, d1 = __builtin_fmaf(Tq[p].y, tb1, 1.0f);
      float n2 = Tq[p].z + tb2, d2 = __builtin_fmaf(Tq[p].z, tb2, 1.0f);
      float n3 = Tq[p].w + tb3, d3 = __builtin_fmaf(Tq[p].w, tb3, 1.0f);
      float m0 = n0*fast_rcp(d0);
      float m1 = n1*fast_rcp(d1);
      float m2 = n2*fast_rcp(d2);
      float m3 = n3*fast_rcp(d3);
      float sc = m0*wv4.x + m1*wv4.y + m2*wv4.z + m3*wv4.w;
      sc += __shfl_xor(sc,1); sc += __shfl_xor(sc,2);
      sc += __shfl_xor(sc,4); sc += __shfl_xor(sc,8);
      float masked = s1v[p]*sc - (1.0f - s1v[p])*1e12f;
      float ex = __expf(masked);
      sum_acc += ex;
      ax = __builtin_fmaf(ex, hq[p].x, ax);
      ay = __builtin_fmaf(ex, hq[p].y, ay);
      az = __builtin_fmaf(ex, hq[p].z, az);
      aw = __builtin_fmaf(ex, hq[p].w, aw);
    }
    // reduce the 4 sixteen-groups of the wave
    ax += __shfl_xor(ax,16); ax += __shfl_xor(ax,32);
    ay += __shfl_xor(ay,16); ay += __shfl_xor(ay,32);
    az += __shfl_xor(az,16); az += __shfl_xor(az,32);
    aw += __shfl_xor(aw,16); aw += __shfl_xor(aw,32);
    sum_acc += __shfl_xor(sum_acc,16); sum_acc += __shfl_xor(sum_acc,32);
    if (lane < 16){
      atomicAdd(&attn_acc[cur][e4+0], ax);
      atomicAdd(&attn_acc[cur][e4+1], ay);
      atomicAdd(&attn_acc[cur][e4+2], az);
      atomicAdd(&attn_acc[cur][e4+3], aw);
      if (lane==0) atomicAdd(&attn_acc[cur][64], sum_acc);
    }
    __syncthreads();

    // ---- phase B: every wave computes rnew redundantly (e = lane) ----
    float asum = attn_acc[cur][lane];
    float tot  = attn_acc[cur][64];
    float rtv  = tanh_fast(rt_buf[cur][lane]);
    float rnew = __builtin_fmaf(asum, fast_rcp(tot), rtv);
    if (wave==0 && s==idx2) rn_keep = rnew;
    {
      int k0 = (wave&7)*8;
      float acc = 0.f;
      #pragma unroll
      for (int j=0;j<8;++j)
        acc = __builtin_fmaf(bcast_lane(rnew, k0+j), wch[j], acc);
      if (wave < 8) atomicAdd(&rw_buf[nxt][lane], acc);
      else          atomicAdd(&rt_buf[nxt][lane], acc);
    }
    __syncthreads();
  }
  if (wave==0) rn_cap[b*E + lane] = rn_keep;
}

// ---------------------------------------------------------------------------
// K4: final MLP. 64 blocks x 128 threads.
// ---------------------------------------------------------------------------
__global__ __launch_bounds__(128) void final_kernel(
  const float* __restrict__ rn_cap, const float* __restrict__ hn_cap,
  const float* __restrict__ wp, const float* __restrict__ wx,
  const float* __restrict__ l1W, const float* __restrict__ l1b,
  const float* __restrict__ lW, const float* __restrict__ lb,
  float* __restrict__ out)
{
  const int b = blockIdx.x, t = threadIdx.x;
  __shared__ float rn[E], hn[E], hid1[E], hid2[128];
  if (t<E){ rn[t]=rn_cap[b*E+t]; hn[t]=hn_cap[b*E+t]; }
  __syncthreads();
  if (t<E){
    float a0=0,a1=0;
    #pragma unroll
    for (int k=0;k<E;++k){
      a0 += rn[k]*wp[k*E+t];
      a1 += hn[k]*wx[k*E+t];
    }
    hid1[t] = tanh_fast(a0+a1);
  }
  __syncthreads();
  {
    float acc = l1b[t];
    #pragma unroll
    for (int k=0;k<E;++k) acc += hid1[k]*l1W[t*E+k];
    hid2[t] = tanh_fast(acc);
  }
  __syncthreads();
  if (t<4){
    float acc = lb[t];
    #pragma unroll
    for (int k=0;k<128;++k) acc += hid2[k]*lW[t*128+k];
    out[b*4+t] = acc;
  }
}

extern "C" void kernel_launch(void* const* d_in, const int* in_sizes, int n_in,
                              void* d_out, int out_size, void* d_ws, size_t ws_size,
                              hipStream_t stream)
{
  const int*   sent1 = (const int*)  d_in[0];
  const int*   sent2 = (const int*)  d_in[1];
  const int*   s1len = (const int*)  d_in[2];
  const int*   s2len = (const int*)  d_in[3];
  const float* s1s   = (const float*)d_in[4];
  const float* emb   = (const float*)d_in[6];
  const float* Wih1  = (const float*)d_in[7];
  const float* Whh1  = (const float*)d_in[8];
  const float* bih1  = (const float*)d_in[9];
  const float* bhh1  = (const float*)d_in[10];
  const float* Wih2  = (const float*)d_in[11];
  const float* Whh2  = (const float*)d_in[12];
  const float* bih2  = (const float*)d_in[13];
  const float* bhh2  = (const float*)d_in[14];
  const float* wy    = (const float*)d_in[15];
  const float* wh    = (const float*)d_in[16];
  const float* w     = (const float*)d_in[17];
  const float* wp    = (const float*)d_in[18];
  const float* wx    = (const float*)d_in[19];
  const float* wr    = (const float*)d_in[20];
  const float* wt    = (const float*)d_in[21];
  const float* l1W   = (const float*)d_in[22];
  const float* l1b   = (const float*)d_in[23];
  const float* lW    = (const float*)d_in[24];
  const float* lb    = (const float*)d_in[25];
  float* out = (float*)d_out;

  float* ws  = (float*)d_ws;
  float* gx1 = ws;                         // 64*384*256 = 6291456 floats
  float* gx2 = gx1 + 6291456;
  float* h1  = gx2 + 6291456;              // 64*384*64 = 1572864
  float* outa= h1  + 1572864;
  float* Tg  = outa + 1572864;
  float* rnc = Tg  + 1572864;              // 4096
  float* hnc = rnc + 4096;

  hipLaunchKernelGGL(gx_kernel, dim3(512), dim3(256), 0, stream,
    sent1, sent2, emb, Wih1, bih1, bhh1, Wih2, bih2, bhh2, gx1, gx2);
  hipLaunchKernelGGL(lstm_kernel, dim3(64), dim3(256), 0, stream,
    gx1, gx2, Whh1, Whh2, s1len, s2len, h1, outa, hnc);
  hipLaunchKernelGGL(base_kernel, dim3(1536), dim3(256), 0, stream,
    h1, outa, wy, wh, Tg);
  hipLaunchKernelGGL(attn_kernel, dim3(64), dim3(1024), 0, stream,
    h1, Tg, w, wr, wt, s1s, s2len, rnc);
  hipLaunchKernelGGL(final_kernel, dim3(64), dim3(128), 0, stream,
    rnc, hnc, wp, wx, l1W, l1b, lW, lb, out);
}

// Round 4
// 1707.418 us; speedup vs baseline: 1.4527x; 1.4527x over previous
//
#include <hip/hip_runtime.h>

#define E 64
#define D 50
#define SS 384
#define G4 256   // 4*E

__device__ __forceinline__ float fast_rcp(float x){ return __builtin_amdgcn_rcpf(x); }
__device__ __forceinline__ float tanh_fast(float x){
  // tanh(x) = 1 - 2/(exp(2x)+1)
  float e = __expf(2.0f*x);
  return 1.0f - 2.0f*fast_rcp(e + 1.0f);
}
__device__ __forceinline__ float sigmoid_fast(float x){
  return fast_rcp(1.0f + __expf(-x));
}
// whole-wave rotate via DPP (VALU pipe, NOT the DS pipe).
// wave_ror:1 semantics (per the canonical row_shr scan idiom): lane i
// receives the value of lane (i-1)&63 — data moves toward HIGHER lanes.
__device__ __forceinline__ float ror1(float x){
  return __int_as_float(__builtin_amdgcn_update_dpp(
      0, __float_as_int(x), 0x13C /*wave_ror:1*/, 0xF, 0xF, false));
}
__device__ __forceinline__ float rdlane(float v, int l){
  return __int_as_float(__builtin_amdgcn_readlane(__float_as_int(v), l));
}

// ---------------------------------------------------------------------------
// K0: gx[b,s,j] = bias[j] + sum_k emb[sent[b,s],k] * Wih[j,k]   (both LSTMs)
// ---------------------------------------------------------------------------
__global__ __launch_bounds__(256) void gx_kernel(
  const int* __restrict__ sent1, const int* __restrict__ sent2,
  const float* __restrict__ emb,
  const float* __restrict__ Wih1, const float* __restrict__ bih1, const float* __restrict__ bhh1,
  const float* __restrict__ Wih2, const float* __restrict__ bih2, const float* __restrict__ bhh2,
  float* __restrict__ gx1, float* __restrict__ gx2)
{
  const int bb    = blockIdx.x;     // 0..511
  const int which = bb >> 8;
  const int chunk = bb & 255;
  const int j     = threadIdx.x;
  const int*   sent = which ? sent2 : sent1;
  const float* Wih  = which ? Wih2  : Wih1;
  const float* bA   = which ? bih2  : bih1;
  const float* bB   = which ? bhh2  : bhh1;
  float*       gx   = which ? gx2   : gx1;

  float wih[D];
  #pragma unroll
  for (int k=0;k<D;k+=2){
    float2 v = *(const float2*)&Wih[j*D+k];
    wih[k]=v.x; wih[k+1]=v.y;
  }
  const float bias = bA[j] + bB[j];

  __shared__ __align__(16) float xb[8][52];
  const int row0 = chunk*96;
  for (int c=0;c<12;++c){
    const int r0 = row0 + c*8;
    #pragma unroll
    for (int q=0;q<2;++q){
      int tt = j + q*256;
      if (tt < 400){
        int r = tt/50;
        int k = tt - r*50;
        int idx = sent[r0 + r];
        xb[r][k] = emb[(size_t)idx*D + k];
      }
    }
    __syncthreads();
    for (int r=0;r<8;++r){
      float a0=bias, a1=0.f;
      #pragma unroll
      for (int k=0;k<48;k+=4){
        float4 xv = *(const float4*)&xb[r][k];
        a0 += xv.x*wih[k]   + xv.y*wih[k+1];
        a1 += xv.z*wih[k+2] + xv.w*wih[k+3];
      }
      a0 += xb[r][48]*wih[48];
      a1 += xb[r][49]*wih[49];
      gx[(size_t)(r0+r)*G4 + j] = a0+a1;
    }
    __syncthreads();
  }
}

// ---------------------------------------------------------------------------
// K1: both LSTM recurrences. 64 blocks x 256 threads (4 waves).
// h broadcast replaced by DPP rotate-MAC (ror1: lane i <- lane i-1, so the
// rotating operand holds h[(lane-i)&63] at iter i; tables indexed to match).
// ---------------------------------------------------------------------------
__global__ __launch_bounds__(256) void lstm_kernel(
  const float* __restrict__ gx1, const float* __restrict__ gx2,
  const float* __restrict__ Whh1, const float* __restrict__ Whh2,
  const int* __restrict__ s1_len, const int* __restrict__ s2_len,
  float* __restrict__ h1_all, float* __restrict__ out_all,
  float* __restrict__ hn_cap)
{
  const int b = blockIdx.x;
  const int j = threadIdx.x;
  const int lane = j & 63;
  const int wv = j >> 6;
  __shared__ float h_lds[64];
  __shared__ float gates[256];

  float whht[64];                       // whht[i] = Whh[j][(lane-i)&63] (ror direction)
  #pragma unroll
  for (int i=0;i<32;++i){
    whht[i]    = Whh1[j*64 + ((lane-i)&63)];
    whht[i+32] = Whh1[j*64 + ((lane-i+32)&63)];
  }

  const int is_g = (wv==2);             // wave-uniform: gate 'g' uses tanh
  float c_reg=0.f, gh=0.f, gc=0.f, hn=0.f;
  int idx1=0, idx2=0;
  if (j<64){ idx1=s1_len[b*64+j]; idx2=s2_len[b*64+j]; h_lds[j]=0.f; }
  __syncthreads();

  // ---- LSTM1 ----
  {
    const float* gx = gx1 + (size_t)b*SS*G4;
    float* hout = h1_all + (size_t)b*SS*E;
    float gx_cur = gx[j];
    float gx_n1  = gx[G4 + j];
    for (int s=0;s<SS;++s){
      int sn2 = (s+2<SS)? s+2 : SS-1;
      float gx_n2 = gx[(size_t)sn2*G4 + j];
      float hr  = h_lds[lane];          // iter i holds h[(lane-i)&63]
      float hr2 = h_lds[lane^32];       // iter i holds h[(lane-i+32)&63]
      float g0 = gx_cur, g1 = 0.f;
      #pragma unroll
      for (int i=0;i<32;++i){
        g0 = __builtin_fmaf(hr,  whht[i],    g0);
        g1 = __builtin_fmaf(hr2, whht[i+32], g1);
        hr = ror1(hr); hr2 = ror1(hr2);
      }
      float g = g0 + g1;
      gates[j] = is_g ? tanh_fast(g) : sigmoid_fast(g);
      __syncthreads();
      if (j<64){
        float gi=gates[j], gf=gates[64+j], gg=gates[128+j], go=gates[192+j];
        c_reg = gf*c_reg + gi*gg;
        float h = go * tanh_fast(c_reg);
        h_lds[j] = h;
        hout[(size_t)s*E + j] = h;
        if (s==idx1){ gh=h; gc=c_reg; }
      }
      gx_cur = gx_n1; gx_n1 = gx_n2;
      __syncthreads();
    }
  }
  // ---- LSTM2 ----
  #pragma unroll
  for (int i=0;i<32;++i){
    whht[i]    = Whh2[j*64 + ((lane-i)&63)];
    whht[i+32] = Whh2[j*64 + ((lane-i+32)&63)];
  }
  if (j<64){ h_lds[j]=gh; c_reg=gc; }
  __syncthreads();
  {
    const float* gx = gx2 + (size_t)b*SS*G4;
    float* hout = out_all + (size_t)b*SS*E;
    float gx_cur = gx[j];
    float gx_n1  = gx[G4 + j];
    for (int s=0;s<SS;++s){
      int sn2 = (s+2<SS)? s+2 : SS-1;
      float gx_n2 = gx[(size_t)sn2*G4 + j];
      float hr  = h_lds[lane];
      float hr2 = h_lds[lane^32];
      float g0 = gx_cur, g1 = 0.f;
      #pragma unroll
      for (int i=0;i<32;++i){
        g0 = __builtin_fmaf(hr,  whht[i],    g0);
        g1 = __builtin_fmaf(hr2, whht[i+32], g1);
        hr = ror1(hr); hr2 = ror1(hr2);
      }
      float g = g0 + g1;
      gates[j] = is_g ? tanh_fast(g) : sigmoid_fast(g);
      __syncthreads();
      if (j<64){
        float gi=gates[j], gf=gates[64+j], gg=gates[128+j], go=gates[192+j];
        c_reg = gf*c_reg + gi*gg;
        float h = go * tanh_fast(c_reg);
        h_lds[j] = h;
        hout[(size_t)s*E + j] = h;
        if (s==idx2) hn = h;
      }
      gx_cur = gx_n1; gx_n1 = gx_n2;
      __syncthreads();
    }
  }
  if (j<64) hn_cap[b*64+j] = hn;
}

// ---------------------------------------------------------------------------
// K2: E_g[row,f] = exp( 2*(h1[row]@wy + out[row]@wh)[f] )
// (exp folded here so attn can use tanh(x+y) = 1 - 2/(exp(2x)exp(2y)+1))
// ---------------------------------------------------------------------------
__global__ __launch_bounds__(256) void base_kernel(
  const float* __restrict__ h1_all, const float* __restrict__ out_all,
  const float* __restrict__ wy, const float* __restrict__ wh,
  float* __restrict__ E_g)
{
  const int t = threadIdx.x;
  const int wave = t>>6, lane = t&63;
  float wyc[E], whc[E];
  #pragma unroll
  for (int e=0;e<E;++e){ wyc[e]=wy[e*E+lane]; whc[e]=wh[e*E+lane]; }
  const int row0 = blockIdx.x*16 + wave*4;
  for (int r=0;r<4;++r){
    int row = row0 + r;
    float hv = h1_all[(size_t)row*E + lane];
    float ov = out_all[(size_t)row*E + lane];
    float a0=0,a1=0;
    #pragma unroll
    for (int e=0;e<E;++e){
      a0 += rdlane(hv,e)*wyc[e];
      a1 += rdlane(ov,e)*whc[e];
    }
    E_g[(size_t)row*E + lane] = __expf(2.0f*(a0+a1));
  }
}

// ---------------------------------------------------------------------------
// K3: attention scan. 64 blocks x 384 threads (6 waves), 384 steps.
// lane = s-row: score is fully THREAD-LOCAL (no shuffles).
//   m[e] = tanh(base+rw) = 1 - 2*rcp(E[s,e]*R[e]+1), R[e]=exp(2*rw[e])
//   score = sum w[e]*m[e] = WSUM + sum (-2*w[e])*rcp(...)
// acc[e] = sum_s ex*h via DPP rotate-MAC (VALU, no DS).
// Cross-wave: packed float2 b64 partial exchange, 2 barriers/step.
// ---------------------------------------------------------------------------
__global__ __launch_bounds__(384, 2) void attn_kernel(
  const float* __restrict__ h1_all, const float* __restrict__ E_all,
  const float* __restrict__ w, const float* __restrict__ wr, const float* __restrict__ wt,
  const float* __restrict__ s1_s, const int* __restrict__ s2_len,
  float* __restrict__ rn_cap)
{
  const int b = blockIdx.x;
  const int t = threadIdx.x;
  const int wv = t>>6, lane = t&63;
  const int row = wv*64 + lane;

  __shared__ float2 accP[6*64];    // {acc[e]-partial, tot-partial} per wave
  __shared__ float2 rwrtP[6*64];   // {rw-partial, rt-partial} per wave

  const float* h1b = h1_all + (size_t)b*SS*E;
  const float* Eb  = E_all  + (size_t)b*SS*E;

  // ---- preload (once) ----
  float Ee[64];                               // E row for my s-row
  #pragma unroll
  for (int k=0;k<64;k+=4){
    float4 v = *(const float4*)&Eb[(size_t)row*E + k];
    Ee[k]=v.x; Ee[k+1]=v.y; Ee[k+2]=v.z; Ee[k+3]=v.w;
  }
  float ht[64];                               // ht[i] = h[row (lane-i)&63][lane] (ror direction)
  #pragma unroll
  for (int i=0;i<32;++i){
    ht[i]    = h1b[(size_t)(wv*64 + ((lane-i)&63))*E + lane];
    ht[i+32] = h1b[(size_t)(wv*64 + ((lane-i+32)&63))*E + lane];
  }
  float w2v[64]; float WSUM = 0.f;
  #pragma unroll
  for (int k=0;k<64;k+=4){
    float4 v = *(const float4*)&w[k];
    w2v[k]=-2.f*v.x; w2v[k+1]=-2.f*v.y; w2v[k+2]=-2.f*v.z; w2v[k+3]=-2.f*v.w;
    WSUM += (v.x+v.y)+(v.z+v.w);
  }
  const float s1v = s1_s[b*SS + row];
  const int  idx2 = s2_len[b*E + lane];
  // GEMV k-chunk for this wave (rnew@wr, rnew@wt)
  const int k0  = (wv<4)? wv*11 : 44+(wv-4)*10;
  const int cnt = (wv<4)? 11 : 10;
  float wrch[11], wtch[11];
  #pragma unroll
  for (int jj=0;jj<11;++jj){
    int kk = k0 + ((jj<cnt)? jj : 0);
    wrch[jj] = wr[kk*E + lane];
    wtch[jj] = wt[kk*E + lane];
  }

  rwrtP[t] = make_float2(0.f, 0.f);   // r0 = 0 -> rw=0, rt=0
  __syncthreads();

  float rn_keep = 0.f;
  for (int s=0;s<SS;++s){
    // ---- A-pre: reduce rw/rt partials (redundant per wave, 6 b64 reads) ----
    float rwl=0.f, rtl=0.f;
    #pragma unroll
    for (int q=0;q<6;++q){ float2 v = rwrtP[q*64+lane]; rwl+=v.x; rtl+=v.y; }
    float Rl = __expf(2.0f*rwl);      // R[e=lane]

    // ---- score (thread-local over e) ----
    float sc0=0.f, sc1=0.f, sc2=0.f, sc3=0.f;
    #pragma unroll
    for (int e=0;e<64;e+=4){
      float r0=rdlane(Rl,e),   r1=rdlane(Rl,e+1);
      float r2=rdlane(Rl,e+2), r3=rdlane(Rl,e+3);
      sc0 = __builtin_fmaf(w2v[e],   fast_rcp(__builtin_fmaf(Ee[e],  r0,1.f)), sc0);
      sc1 = __builtin_fmaf(w2v[e+1], fast_rcp(__builtin_fmaf(Ee[e+1],r1,1.f)), sc1);
      sc2 = __builtin_fmaf(w2v[e+2], fast_rcp(__builtin_fmaf(Ee[e+2],r2,1.f)), sc2);
      sc3 = __builtin_fmaf(w2v[e+3], fast_rcp(__builtin_fmaf(Ee[e+3],r3,1.f)), sc3);
    }
    float sc = WSUM + ((sc0+sc1)+(sc2+sc3));
    float masked = s1v*sc - (1.f - s1v)*1e12f;
    float ex = __expf(masked);        // |sc| <= sum|w| ~ 51 -> fp32 safe

    // ---- rotate-MAC: acc[e=lane] += ex[row]*h[row][lane], tot += ex ----
    float exr  = ex;                  // iter i: ex[row (lane-i)&63]
    float exr2 = __shfl_xor(ex, 32);  // iter i: ex[row (lane-i+32)&63]
    float acc=0.f, tot=0.f;
    #pragma unroll
    for (int i=0;i<32;++i){
      acc = __builtin_fmaf(exr,  ht[i],    acc);
      acc = __builtin_fmaf(exr2, ht[i+32], acc);
      tot += exr + exr2;
      exr = ror1(exr); exr2 = ror1(exr2);
    }
    accP[wv*64+lane] = make_float2(acc, tot);
    __syncthreads();

    // ---- phase C: reduce acc/tot, rnew, distributed GEMV ----
    float av=0.f, tv=0.f;
    #pragma unroll
    for (int q=0;q<6;++q){ float2 v = accP[q*64+lane]; av+=v.x; tv+=v.y; }
    float rnew = __builtin_fmaf(av, fast_rcp(tv), tanh_fast(rtl));
    if (wv==0 && s==idx2) rn_keep = rnew;
    float rwp=0.f, rtp=0.f;
    #pragma unroll
    for (int jj=0;jj<11;++jj){
      if (jj<cnt){
        float rv = rdlane(rnew, k0+jj);
        rwp = __builtin_fmaf(rv, wrch[jj], rwp);
        rtp = __builtin_fmaf(rv, wtch[jj], rtp);
      }
    }
    rwrtP[wv*64+lane] = make_float2(rwp, rtp);
    __syncthreads();
  }
  if (wv==0) rn_cap[b*E + lane] = rn_keep;
}

// ---------------------------------------------------------------------------
// K4: final MLP. 64 blocks x 128 threads.
// ---------------------------------------------------------------------------
__global__ __launch_bounds__(128) void final_kernel(
  const float* __restrict__ rn_cap, const float* __restrict__ hn_cap,
  const float* __restrict__ wp, const float* __restrict__ wx,
  const float* __restrict__ l1W, const float* __restrict__ l1b,
  const float* __restrict__ lW, const float* __restrict__ lb,
  float* __restrict__ out)
{
  const int b = blockIdx.x, t = threadIdx.x;
  __shared__ float rn[E], hn[E], hid1[E], hid2[128];
  if (t<E){ rn[t]=rn_cap[b*E+t]; hn[t]=hn_cap[b*E+t]; }
  __syncthreads();
  if (t<E){
    float a0=0,a1=0;
    #pragma unroll
    for (int k=0;k<E;++k){
      a0 += rn[k]*wp[k*E+t];
      a1 += hn[k]*wx[k*E+t];
    }
    hid1[t] = tanh_fast(a0+a1);
  }
  __syncthreads();
  {
    float acc = l1b[t];
    #pragma unroll
    for (int k=0;k<E;++k) acc += hid1[k]*l1W[t*E+k];
    hid2[t] = tanh_fast(acc);
  }
  __syncthreads();
  if (t<4){
    float acc = lb[t];
    #pragma unroll
    for (int k=0;k<128;++k) acc += hid2[k]*lW[t*128+k];
    out[b*4+t] = acc;
  }
}

extern "C" void kernel_launch(void* const* d_in, const int* in_sizes, int n_in,
                              void* d_out, int out_size, void* d_ws, size_t ws_size,
                              hipStream_t stream)
{
  const int*   sent1 = (const int*)  d_in[0];
  const int*   sent2 = (const int*)  d_in[1];
  const int*   s1len = (const int*)  d_in[2];
  const int*   s2len = (const int*)  d_in[3];
  const float* s1s   = (const float*)d_in[4];
  const float* emb   = (const float*)d_in[6];
  const float* Wih1  = (const float*)d_in[7];
  const float* Whh1  = (const float*)d_in[8];
  const float* bih1  = (const float*)d_in[9];
  const float* bhh1  = (const float*)d_in[10];
  const float* Wih2  = (const float*)d_in[11];
  const float* Whh2  = (const float*)d_in[12];
  const float* bih2  = (const float*)d_in[13];
  const float* bhh2  = (const float*)d_in[14];
  const float* wy    = (const float*)d_in[15];
  const float* wh    = (const float*)d_in[16];
  const float* w     = (const float*)d_in[17];
  const float* wp    = (const float*)d_in[18];
  const float* wx    = (const float*)d_in[19];
  const float* wr    = (const float*)d_in[20];
  const float* wt    = (const float*)d_in[21];
  const float* l1W   = (const float*)d_in[22];
  const float* l1b   = (const float*)d_in[23];
  const float* lW    = (const float*)d_in[24];
  const float* lb    = (const float*)d_in[25];
  float* out = (float*)d_out;

  float* ws  = (float*)d_ws;
  float* gx1 = ws;                         // 64*384*256 = 6291456 floats
  float* gx2 = gx1 + 6291456;
  float* h1  = gx2 + 6291456;              // 64*384*64 = 1572864
  float* outa= h1  + 1572864;
  float* Eg  = outa + 1572864;
  float* rnc = Eg  + 1572864;              // 4096
  float* hnc = rnc + 4096;

  hipLaunchKernelGGL(gx_kernel, dim3(512), dim3(256), 0, stream,
    sent1, sent2, emb, Wih1, bih1, bhh1, Wih2, bih2, bhh2, gx1, gx2);
  hipLaunchKernelGGL(lstm_kernel, dim3(64), dim3(256), 0, stream,
    gx1, gx2, Whh1, Whh2, s1len, s2len, h1, outa, hnc);
  hipLaunchKernelGGL(base_kernel, dim3(1536), dim3(256), 0, stream,
    h1, outa, wy, wh, Eg);
  hipLaunchKernelGGL(attn_kernel, dim3(64), dim3(384), 0, stream,
    h1, Eg, w, wr, wt, s1s, s2len, rnc);
  hipLaunchKernelGGL(final_kernel, dim3(64), dim3(128), 0, stream,
    rnc, hnc, wp, wx, l1W, l1b, lW, lb, out);
}

// Round 5
// 1707.378 us; speedup vs baseline: 1.4527x; 1.0000x over previous
//
#include <hip/hip_runtime.h>

#define E 64
#define D 50
#define SS 384
#define G4 256   // 4*E

__device__ __forceinline__ float fast_rcp(float x){ return __builtin_amdgcn_rcpf(x); }
__device__ __forceinline__ float tanh_fast(float x){
  // tanh(x) = 1 - 2/(exp(2x)+1)
  float e = __expf(2.0f*x);
  return 1.0f - 2.0f*fast_rcp(e + 1.0f);
}
__device__ __forceinline__ float sigmoid_fast(float x){
  return fast_rcp(1.0f + __expf(-x));
}
// whole-wave rotate via DPP (VALU pipe, NOT the DS pipe).
// wave_ror:1: lane i receives the value of lane (i-1)&63.
__device__ __forceinline__ float ror1(float x){
  return __int_as_float(__builtin_amdgcn_update_dpp(
      0, __float_as_int(x), 0x13C /*wave_ror:1*/, 0xF, 0xF, false));
}
__device__ __forceinline__ float rdlane(float v, int l){
  return __int_as_float(__builtin_amdgcn_readlane(__float_as_int(v), l));
}

// ---------------------------------------------------------------------------
// K0: gx[b,s,j] = bias[j] + sum_k emb[sent[b,s],k] * Wih[j,k]   (both LSTMs)
// ---------------------------------------------------------------------------
__global__ __launch_bounds__(256, 1) void gx_kernel(
  const int* __restrict__ sent1, const int* __restrict__ sent2,
  const float* __restrict__ emb,
  const float* __restrict__ Wih1, const float* __restrict__ bih1, const float* __restrict__ bhh1,
  const float* __restrict__ Wih2, const float* __restrict__ bih2, const float* __restrict__ bhh2,
  float* __restrict__ gx1, float* __restrict__ gx2)
{
  const int bb    = blockIdx.x;     // 0..511
  const int which = bb >> 8;
  const int chunk = bb & 255;
  const int j     = threadIdx.x;
  const int*   sent = which ? sent2 : sent1;
  const float* Wih  = which ? Wih2  : Wih1;
  const float* bA   = which ? bih2  : bih1;
  const float* bB   = which ? bhh2  : bhh1;
  float*       gx   = which ? gx2   : gx1;

  float wih[D];
  #pragma unroll
  for (int k=0;k<D;k+=2){
    float2 v = *(const float2*)&Wih[j*D+k];
    wih[k]=v.x; wih[k+1]=v.y;
  }
  const float bias = bA[j] + bB[j];

  __shared__ __align__(16) float xb[8][52];
  const int row0 = chunk*96;
  for (int c=0;c<12;++c){
    const int r0 = row0 + c*8;
    #pragma unroll
    for (int q=0;q<2;++q){
      int tt = j + q*256;
      if (tt < 400){
        int r = tt/50;
        int k = tt - r*50;
        int idx = sent[r0 + r];
        xb[r][k] = emb[(size_t)idx*D + k];
      }
    }
    __syncthreads();
    for (int r=0;r<8;++r){
      float a0=bias, a1=0.f;
      #pragma unroll
      for (int k=0;k<48;k+=4){
        float4 xv = *(const float4*)&xb[r][k];
        a0 += xv.x*wih[k]   + xv.y*wih[k+1];
        a1 += xv.z*wih[k+2] + xv.w*wih[k+3];
      }
      a0 += xb[r][48]*wih[48];
      a1 += xb[r][49]*wih[49];
      gx[(size_t)(r0+r)*G4 + j] = a0+a1;
    }
    __syncthreads();
  }
}

// ---------------------------------------------------------------------------
// K1: both LSTM recurrences. 64 blocks x 256 threads (4 waves).
// DPP rotate-MAC; (256,1) so the 64-entry Whh table never spills.
// ---------------------------------------------------------------------------
__global__ __launch_bounds__(256, 1) void lstm_kernel(
  const float* __restrict__ gx1, const float* __restrict__ gx2,
  const float* __restrict__ Whh1, const float* __restrict__ Whh2,
  const int* __restrict__ s1_len, const int* __restrict__ s2_len,
  float* __restrict__ h1_all, float* __restrict__ out_all,
  float* __restrict__ hn_cap)
{
  const int b = blockIdx.x;
  const int j = threadIdx.x;
  const int lane = j & 63;
  const int wv = j >> 6;
  __shared__ float h_lds[64];
  __shared__ float gates[256];

  float whht[64];                       // whht[i] = Whh[j][(lane-i)&63] (ror direction)
  #pragma unroll
  for (int i=0;i<32;++i){
    whht[i]    = Whh1[j*64 + ((lane-i)&63)];
    whht[i+32] = Whh1[j*64 + ((lane-i+32)&63)];
  }

  const int is_g = (wv==2);             // wave-uniform: gate 'g' uses tanh
  float c_reg=0.f, gh=0.f, gc=0.f, hn=0.f;
  int idx1=0, idx2=0;
  if (j<64){ idx1=s1_len[b*64+j]; idx2=s2_len[b*64+j]; h_lds[j]=0.f; }
  __syncthreads();

  // ---- LSTM1 ----
  {
    const float* gx = gx1 + (size_t)b*SS*G4;
    float* hout = h1_all + (size_t)b*SS*E;
    float gx_cur = gx[j];
    float gx_n1  = gx[G4 + j];
    for (int s=0;s<SS;++s){
      int sn2 = (s+2<SS)? s+2 : SS-1;
      float gx_n2 = gx[(size_t)sn2*G4 + j];
      float hr  = h_lds[lane];          // iter i holds h[(lane-i)&63]
      float hr2 = h_lds[lane^32];       // iter i holds h[(lane-i+32)&63]
      float g0 = gx_cur, g1 = 0.f;
      #pragma unroll
      for (int i=0;i<32;++i){
        g0 = __builtin_fmaf(hr,  whht[i],    g0);
        g1 = __builtin_fmaf(hr2, whht[i+32], g1);
        hr = ror1(hr); hr2 = ror1(hr2);
      }
      float g = g0 + g1;
      gates[j] = is_g ? tanh_fast(g) : sigmoid_fast(g);
      __syncthreads();
      if (j<64){
        float gi=gates[j], gf=gates[64+j], gg=gates[128+j], go=gates[192+j];
        c_reg = gf*c_reg + gi*gg;
        float h = go * tanh_fast(c_reg);
        h_lds[j] = h;
        hout[(size_t)s*E + j] = h;
        if (s==idx1){ gh=h; gc=c_reg; }
      }
      gx_cur = gx_n1; gx_n1 = gx_n2;
      __syncthreads();
    }
  }
  // ---- LSTM2 ----
  #pragma unroll
  for (int i=0;i<32;++i){
    whht[i]    = Whh2[j*64 + ((lane-i)&63)];
    whht[i+32] = Whh2[j*64 + ((lane-i+32)&63)];
  }
  if (j<64){ h_lds[j]=gh; c_reg=gc; }
  __syncthreads();
  {
    const float* gx = gx2 + (size_t)b*SS*G4;
    float* hout = out_all + (size_t)b*SS*E;
    float gx_cur = gx[j];
    float gx_n1  = gx[G4 + j];
    for (int s=0;s<SS;++s){
      int sn2 = (s+2<SS)? s+2 : SS-1;
      float gx_n2 = gx[(size_t)sn2*G4 + j];
      float hr  = h_lds[lane];
      float hr2 = h_lds[lane^32];
      float g0 = gx_cur, g1 = 0.f;
      #pragma unroll
      for (int i=0;i<32;++i){
        g0 = __builtin_fmaf(hr,  whht[i],    g0);
        g1 = __builtin_fmaf(hr2, whht[i+32], g1);
        hr = ror1(hr); hr2 = ror1(hr2);
      }
      float g = g0 + g1;
      gates[j] = is_g ? tanh_fast(g) : sigmoid_fast(g);
      __syncthreads();
      if (j<64){
        float gi=gates[j], gf=gates[64+j], gg=gates[128+j], go=gates[192+j];
        c_reg = gf*c_reg + gi*gg;
        float h = go * tanh_fast(c_reg);
        h_lds[j] = h;
        hout[(size_t)s*E + j] = h;
        if (s==idx2) hn = h;
      }
      gx_cur = gx_n1; gx_n1 = gx_n2;
      __syncthreads();
    }
  }
  if (j<64) hn_cap[b*64+j] = hn;
}

// ---------------------------------------------------------------------------
// K2: E_g[row,f] = exp( 2*(h1[row]@wy + out[row]@wh)[f] )
// (256,1): wyc+whc = 128 VGPRs must NOT spill.
// ---------------------------------------------------------------------------
__global__ __launch_bounds__(256, 1) void base_kernel(
  const float* __restrict__ h1_all, const float* __restrict__ out_all,
  const float* __restrict__ wy, const float* __restrict__ wh,
  float* __restrict__ E_g)
{
  const int t = threadIdx.x;
  const int wave = t>>6, lane = t&63;
  float wyc[E], whc[E];
  #pragma unroll
  for (int e=0;e<E;++e){ wyc[e]=wy[e*E+lane]; whc[e]=wh[e*E+lane]; }
  const int row0 = blockIdx.x*16 + wave*4;
  for (int r=0;r<4;++r){
    int row = row0 + r;
    float hv = h1_all[(size_t)row*E + lane];
    float ov = out_all[(size_t)row*E + lane];
    float a0=0,a1=0;
    #pragma unroll
    for (int e=0;e<E;++e){
      a0 += rdlane(hv,e)*wyc[e];
      a1 += rdlane(ov,e)*whc[e];
    }
    E_g[(size_t)row*E + lane] = __expf(2.0f*(a0+a1));
  }
}

// ---------------------------------------------------------------------------
// K3: attention scan. 64 blocks x 384 threads (6 waves), 384 steps.
// Same verified structure as round 4, but:
//  - __launch_bounds__(384,1): VGPR cap 512 -> Ee[64]+ht[64]+chunks live in
//    registers, NO scratch spills (round 4 spilled ~90 regs at cap 128).
//  - w[] accessed with loop-constant index -> compiler scalar-loads (SGPR),
//    removing the w2v[64] VGPR array entirely.
//    sc = WSUM - 2 * sum_e w[e]*rcp(Ee[e]*R[e]+1)
// ---------------------------------------------------------------------------
__global__ __launch_bounds__(384, 1) void attn_kernel(
  const float* __restrict__ h1_all, const float* __restrict__ E_all,
  const float* __restrict__ w, const float* __restrict__ wr, const float* __restrict__ wt,
  const float* __restrict__ s1_s, const int* __restrict__ s2_len,
  float* __restrict__ rn_cap)
{
  const int b = blockIdx.x;
  const int t = threadIdx.x;
  const int wv = t>>6, lane = t&63;
  const int row = wv*64 + lane;

  __shared__ float2 accP[6*64];    // {acc[e]-partial, tot-partial} per wave
  __shared__ float2 rwrtP[6*64];   // {rw-partial, rt-partial} per wave

  const float* h1b = h1_all + (size_t)b*SS*E;
  const float* Eb  = E_all  + (size_t)b*SS*E;

  // ---- preload (once) ----
  float Ee[64];                               // E row for my s-row
  #pragma unroll
  for (int k=0;k<64;k+=4){
    float4 v = *(const float4*)&Eb[(size_t)row*E + k];
    Ee[k]=v.x; Ee[k+1]=v.y; Ee[k+2]=v.z; Ee[k+3]=v.w;
  }
  float ht[64];                               // ht[i] = h[row (lane-i)&63][lane] (ror direction)
  #pragma unroll
  for (int i=0;i<32;++i){
    ht[i]    = h1b[(size_t)(wv*64 + ((lane-i)&63))*E + lane];
    ht[i+32] = h1b[(size_t)(wv*64 + ((lane-i+32)&63))*E + lane];
  }
  float WSUM = 0.f;
  for (int e=0;e<64;++e) WSUM += w[e];        // uniform -> scalar
  const float s1v = s1_s[b*SS + row];
  const int  idx2 = s2_len[b*E + lane];
  // GEMV k-chunk for this wave (rnew@wr, rnew@wt)
  const int k0  = (wv<4)? wv*11 : 44+(wv-4)*10;
  const int cnt = (wv<4)? 11 : 10;
  float wrch[11], wtch[11];
  #pragma unroll
  for (int jj=0;jj<11;++jj){
    int kk = k0 + ((jj<cnt)? jj : 0);
    wrch[jj] = wr[kk*E + lane];
    wtch[jj] = wt[kk*E + lane];
  }

  rwrtP[t] = make_float2(0.f, 0.f);   // r0 = 0 -> rw=0, rt=0
  __syncthreads();

  float rn_keep = 0.f;
  for (int s=0;s<SS;++s){
    // ---- A-pre: reduce rw/rt partials (redundant per wave, 6 b64 reads) ----
    float rwl=0.f, rtl=0.f;
    #pragma unroll
    for (int q=0;q<6;++q){ float2 v = rwrtP[q*64+lane]; rwl+=v.x; rtl+=v.y; }
    float Rl = __expf(2.0f*rwl);      // R[e=lane]

    // ---- score (thread-local over e; w[e] is a scalar operand) ----
    float sc0=0.f, sc1=0.f, sc2=0.f, sc3=0.f;
    #pragma unroll
    for (int e=0;e<64;e+=4){
      float r0=rdlane(Rl,e),   r1=rdlane(Rl,e+1);
      float r2=rdlane(Rl,e+2), r3=rdlane(Rl,e+3);
      sc0 = __builtin_fmaf(w[e],   fast_rcp(__builtin_fmaf(Ee[e],  r0,1.f)), sc0);
      sc1 = __builtin_fmaf(w[e+1], fast_rcp(__builtin_fmaf(Ee[e+1],r1,1.f)), sc1);
      sc2 = __builtin_fmaf(w[e+2], fast_rcp(__builtin_fmaf(Ee[e+2],r2,1.f)), sc2);
      sc3 = __builtin_fmaf(w[e+3], fast_rcp(__builtin_fmaf(Ee[e+3],r3,1.f)), sc3);
    }
    float sc = WSUM - 2.0f*(((sc0+sc1)+(sc2+sc3)));
    float masked = s1v*sc - (1.f - s1v)*1e12f;
    float ex = __expf(masked);        // |sc| <= sum|w| ~ 51 -> fp32 safe

    // ---- rotate-MAC: acc[e=lane] += ex[row]*h[row][lane], tot += ex ----
    float exr  = ex;                  // iter i: ex[row (lane-i)&63]
    float exr2 = __shfl_xor(ex, 32);  // iter i: ex[row (lane-i+32)&63]
    float acc=0.f, tot=0.f;
    #pragma unroll
    for (int i=0;i<32;++i){
      acc = __builtin_fmaf(exr,  ht[i],    acc);
      acc = __builtin_fmaf(exr2, ht[i+32], acc);
      tot += exr + exr2;
      exr = ror1(exr); exr2 = ror1(exr2);
    }
    accP[wv*64+lane] = make_float2(acc, tot);
    __syncthreads();

    // ---- phase C: reduce acc/tot, rnew, distributed GEMV ----
    float av=0.f, tv=0.f;
    #pragma unroll
    for (int q=0;q<6;++q){ float2 v = accP[q*64+lane]; av+=v.x; tv+=v.y; }
    float rnew = __builtin_fmaf(av, fast_rcp(tv), tanh_fast(rtl));
    if (wv==0 && s==idx2) rn_keep = rnew;
    float rwp=0.f, rtp=0.f;
    #pragma unroll
    for (int jj=0;jj<11;++jj){
      if (jj<cnt){
        float rv = rdlane(rnew, k0+jj);
        rwp = __builtin_fmaf(rv, wrch[jj], rwp);
        rtp = __builtin_fmaf(rv, wtch[jj], rtp);
      }
    }
    rwrtP[wv*64+lane] = make_float2(rwp, rtp);
    __syncthreads();
  }
  if (wv==0) rn_cap[b*E + lane] = rn_keep;
}

// ---------------------------------------------------------------------------
// K4: final MLP. 64 blocks x 128 threads.
// ---------------------------------------------------------------------------
__global__ __launch_bounds__(128, 1) void final_kernel(
  const float* __restrict__ rn_cap, const float* __restrict__ hn_cap,
  const float* __restrict__ wp, const float* __restrict__ wx,
  const float* __restrict__ l1W, const float* __restrict__ l1b,
  const float* __restrict__ lW, const float* __restrict__ lb,
  float* __restrict__ out)
{
  const int b = blockIdx.x, t = threadIdx.x;
  __shared__ float rn[E], hn[E], hid1[E], hid2[128];
  if (t<E){ rn[t]=rn_cap[b*E+t]; hn[t]=hn_cap[b*E+t]; }
  __syncthreads();
  if (t<E){
    float a0=0,a1=0;
    #pragma unroll
    for (int k=0;k<E;++k){
      a0 += rn[k]*wp[k*E+t];
      a1 += hn[k]*wx[k*E+t];
    }
    hid1[t] = tanh_fast(a0+a1);
  }
  __syncthreads();
  {
    float acc = l1b[t];
    #pragma unroll
    for (int k=0;k<E;++k) acc += hid1[k]*l1W[t*E+k];
    hid2[t] = tanh_fast(acc);
  }
  __syncthreads();
  if (t<4){
    float acc = lb[t];
    #pragma unroll
    for (int k=0;k<128;++k) acc += hid2[k]*lW[t*128+k];
    out[b*4+t] = acc;
  }
}

extern "C" void kernel_launch(void* const* d_in, const int* in_sizes, int n_in,
                              void* d_out, int out_size, void* d_ws, size_t ws_size,
                              hipStream_t stream)
{
  const int*   sent1 = (const int*)  d_in[0];
  const int*   sent2 = (const int*)  d_in[1];
  const int*   s1len = (const int*)  d_in[2];
  const int*   s2len = (const int*)  d_in[3];
  const float* s1s   = (const float*)d_in[4];
  const float* emb   = (const float*)d_in[6];
  const float* Wih1  = (const float*)d_in[7];
  const float* Whh1  = (const float*)d_in[8];
  const float* bih1  = (const float*)d_in[9];
  const float* bhh1  = (const float*)d_in[10];
  const float* Wih2  = (const float*)d_in[11];
  const float* Whh2  = (const float*)d_in[12];
  const float* bih2  = (const float*)d_in[13];
  const float* bhh2  = (const float*)d_in[14];
  const float* wy    = (const float*)d_in[15];
  const float* wh    = (const float*)d_in[16];
  const float* w     = (const float*)d_in[17];
  const float* wp    = (const float*)d_in[18];
  const float* wx    = (const float*)d_in[19];
  const float* wr    = (const float*)d_in[20];
  const float* wt    = (const float*)d_in[21];
  const float* l1W   = (const float*)d_in[22];
  const float* l1b   = (const float*)d_in[23];
  const float* lW    = (const float*)d_in[24];
  const float* lb    = (const float*)d_in[25];
  float* out = (float*)d_out;

  float* ws  = (float*)d_ws;
  float* gx1 = ws;                         // 64*384*256 = 6291456 floats
  float* gx2 = gx1 + 6291456;
  float* h1  = gx2 + 6291456;              // 64*384*64 = 1572864
  float* outa= h1  + 1572864;
  float* Eg  = outa + 1572864;
  float* rnc = Eg  + 1572864;              // 4096
  float* hnc = rnc + 4096;

  hipLaunchKernelGGL(gx_kernel, dim3(512), dim3(256), 0, stream,
    sent1, sent2, emb, Wih1, bih1, bhh1, Wih2, bih2, bhh2, gx1, gx2);
  hipLaunchKernelGGL(lstm_kernel, dim3(64), dim3(256), 0, stream,
    gx1, gx2, Whh1, Whh2, s1len, s2len, h1, outa, hnc);
  hipLaunchKernelGGL(base_kernel, dim3(1536), dim3(256), 0, stream,
    h1, outa, wy, wh, Eg);
  hipLaunchKernelGGL(attn_kernel, dim3(64), dim3(384), 0, stream,
    h1, Eg, w, wr, wt, s1s, s2len, rnc);
  hipLaunchKernelGGL(final_kernel, dim3(64), dim3(128), 0, stream,
    rnc, hnc, wp, wx, l1W, l1b, lW, lb, out);
}